// Round 1
// baseline (504.033 us; speedup 1.0000x reference)
//
#include <hip/hip_runtime.h>

// Problem constants (from reference): B=256, L=512, D=768, 54 outputs/row.
#define BATCH 256
#define SEQ   512
#define DIM   768
#define D4    (DIM / 4)   // 192 float4 per row
#define NOUT  54

// ---------------------------------------------------------------------------
// Kernel 1: masked partial sums.
// grid = BATCH * S, block = 256 threads = 4 waves of 64.
// Each wave owns one l at a time (wave-uniform mask test -> skip whole 3KB row
// when mask==0, halving expected HBM traffic). Each lane holds 3 float4
// accumulators spanning D=768. 4-wave LDS reduce, store partial[b][s][0..767].
// ---------------------------------------------------------------------------
__global__ __launch_bounds__(256) void pool_partial_kernel(
    const float* __restrict__ fh, const int* __restrict__ mask,
    float* __restrict__ partial, int S, int Ls)
{
    const int b    = blockIdx.x / S;
    const int s    = blockIdx.x - b * S;
    const int tid  = threadIdx.x;
    const int lane = tid & 63;
    const int grp  = tid >> 6;   // wave id 0..3

    const float4* fh4  = (const float4*)(fh + (size_t)b * SEQ * DIM);
    const int*    mrow = mask + b * SEQ;

    float4 a0 = make_float4(0.f, 0.f, 0.f, 0.f);
    float4 a1 = a0, a2 = a0;

    const int l_end = s * Ls + Ls;
    for (int l = s * Ls + grp; l < l_end; l += 4) {
        const float m = (float)mrow[l];          // wave-uniform
        if (m != 0.0f) {                         // uniform branch: skip fetch
            const float4* row = fh4 + (size_t)l * D4;
            float4 x0 = row[lane];
            float4 x1 = row[lane + 64];
            float4 x2 = row[lane + 128];
            a0.x = fmaf(m, x0.x, a0.x); a0.y = fmaf(m, x0.y, a0.y);
            a0.z = fmaf(m, x0.z, a0.z); a0.w = fmaf(m, x0.w, a0.w);
            a1.x = fmaf(m, x1.x, a1.x); a1.y = fmaf(m, x1.y, a1.y);
            a1.z = fmaf(m, x1.z, a1.z); a1.w = fmaf(m, x1.w, a1.w);
            a2.x = fmaf(m, x2.x, a2.x); a2.y = fmaf(m, x2.y, a2.y);
            a2.z = fmaf(m, x2.z, a2.z); a2.w = fmaf(m, x2.w, a2.w);
        }
    }

    __shared__ float4 red[4][D4];                // 12 KiB
    red[grp][lane]       = a0;
    red[grp][lane + 64]  = a1;
    red[grp][lane + 128] = a2;
    __syncthreads();

    if (tid < D4) {
        float4 r0 = red[0][tid], r1 = red[1][tid], r2 = red[2][tid], r3 = red[3][tid];
        float4 sum = make_float4(r0.x + r1.x + r2.x + r3.x,
                                 r0.y + r1.y + r2.y + r3.y,
                                 r0.z + r1.z + r2.z + r3.z,
                                 r0.w + r1.w + r2.w + r3.w);
        ((float4*)partial)[((size_t)b * S + s) * D4 + tid] = sum;
    }
}

// ---------------------------------------------------------------------------
// Kernel 2: reduce S partials, divide by mask count, 54 dot-products.
// grid = BATCH, block = 256 threads = 4 waves.
// ---------------------------------------------------------------------------
__global__ __launch_bounds__(256) void finalize_kernel(
    const float* __restrict__ partial, const int* __restrict__ mask,
    const float* __restrict__ W13, const float* __restrict__ b13,
    const float* __restrict__ W14, const float* __restrict__ b14,
    float* __restrict__ out, int S)
{
    const int b    = blockIdx.x;
    const int tid  = threadIdx.x;
    const int lane = tid & 63;
    const int wave = tid >> 6;

    // ---- valid-token count (sum of 512 {0,1} ints) ----
    int cnt = mask[b * SEQ + tid] + mask[b * SEQ + 256 + tid];
    for (int off = 32; off; off >>= 1) cnt += __shfl_down(cnt, off);
    __shared__ int wcnt[4];
    if (lane == 0) wcnt[wave] = cnt;

    __shared__ float pooled[DIM];
    __syncthreads();
    const float inv = 1.0f / (float)(wcnt[0] + wcnt[1] + wcnt[2] + wcnt[3]);

    // ---- reduce S segments -> pooled[d] ----
    if (tid < D4) {
        float4 acc = make_float4(0.f, 0.f, 0.f, 0.f);
        const float4* p4 = (const float4*)partial + (size_t)b * S * D4 + tid;
        for (int s = 0; s < S; ++s) {
            float4 v = p4[(size_t)s * D4];
            acc.x += v.x; acc.y += v.y; acc.z += v.z; acc.w += v.w;
        }
        ((float4*)pooled)[tid] =
            make_float4(acc.x * inv, acc.y * inv, acc.z * inv, acc.w * inv);
    }
    __syncthreads();

    // ---- 54 output dot-products, round-robin across the 4 waves ----
    for (int o = wave; o < NOUT; o += 4) {
        const float* Wrow = (o < 52) ? (W13 + (size_t)o * DIM)
                                     : (W14 + (size_t)(o - 52) * DIM);
        const float bias  = (o < 52) ? b13[o] : b14[o - 52];
        float acc = 0.f;
        #pragma unroll
        for (int j = 0; j < 12; ++j) {
            const int d = lane + 64 * j;
            acc = fmaf(pooled[d], Wrow[d], acc);
        }
        for (int off = 32; off; off >>= 1) acc += __shfl_down(acc, off);
        if (lane == 0) out[(size_t)b * NOUT + o] = acc + bias;
    }
}

// ---------------------------------------------------------------------------
// Inputs (setup_inputs order):
//   0: final_hidden  [256,512,768] f32   1: attention_mask [256,512] i32
//   2: W13 [13,4,768] f32               3: b13 [13,4] f32
//   4: W14 [2,768] f32                  5: b14 [2] f32
// Output: [256,54] f32.
// Workspace: partial sums [B][S][D] f32 = 6.29 MB at S=8 (adaptive shrink).
// ---------------------------------------------------------------------------
extern "C" void kernel_launch(void* const* d_in, const int* in_sizes, int n_in,
                              void* d_out, int out_size, void* d_ws, size_t ws_size,
                              hipStream_t stream) {
    const float* fh   = (const float*)d_in[0];
    const int*   mask = (const int*)d_in[1];
    const float* W13  = (const float*)d_in[2];
    const float* b13  = (const float*)d_in[3];
    const float* W14  = (const float*)d_in[4];
    const float* b14  = (const float*)d_in[5];
    float*       out  = (float*)d_out;
    float*       partial = (float*)d_ws;

    int S = 8;  // 2048 blocks -> 8 blocks/CU; shrink if workspace is tight
    while (S > 1 && (size_t)BATCH * S * DIM * sizeof(float) > ws_size) S >>= 1;
    const int Ls = SEQ / S;

    pool_partial_kernel<<<dim3(BATCH * S), dim3(256), 0, stream>>>(
        fh, mask, partial, S, Ls);
    finalize_kernel<<<dim3(BATCH), dim3(256), 0, stream>>>(
        partial, mask, W13, b13, W14, b14, out, S);
}

// Round 2
// 499.142 us; speedup vs baseline: 1.0098x; 1.0098x over previous
//
#include <hip/hip_runtime.h>

// Problem constants (from reference): B=256, L=512, D=768, 54 outputs/row.
#define BATCH 256
#define SEQ   512
#define DIM   768
#define D4    (DIM / 4)   // 192 float4 per row
#define NOUT  54

// ---------------------------------------------------------------------------
// Kernel 1: masked partial sums, compacted-list version.
// grid = BATCH * S, block = 256 threads = 4 waves of 64.
//
// Phase A: ballot-compact the active (mask==1) row indices of this block's
//   L-segment into LDS (removes the per-iteration mask-load -> branch
//   dependency that throttled outstanding VMEM in round 1).
// Phase B: branch-free streaming loop, 2 rows per wave-iteration = 6
//   independent 1KB coalesced loads in flight per wave. mask values are
//   {0,1}, so active rows are pure adds (no multiply needed).
// Phase C: 4-wave LDS tree reduce, write partial[b][s][0..767].
// ---------------------------------------------------------------------------
__global__ __launch_bounds__(256) void pool_partial_kernel(
    const float* __restrict__ fh, const int* __restrict__ mask,
    float* __restrict__ partial, int S, int Ls)
{
    const int b    = blockIdx.x / S;
    const int s    = blockIdx.x - b * S;
    const int tid  = threadIdx.x;
    const int lane = tid & 63;
    const int grp  = tid >> 6;   // wave id 0..3

    __shared__ int list[128];                       // active l's (Ls <= 128)
    __shared__ unsigned long long balls[2];

    const int base_l = s * Ls;
    const int nw     = Ls >> 6;                     // compaction waves: 1 or 2

    int my_m = 0, my_l = 0;
    unsigned long long my_ball = 0;
    if (grp < nw) {
        my_l = base_l + tid;
        my_m = mask[b * SEQ + my_l];
        my_ball = __ballot(my_m != 0);
        if (lane == 0) balls[grp] = my_ball;
    }
    __syncthreads();

    int n = __popcll(balls[0]);
    if (nw > 1) n += __popcll(balls[1]);

    if (grp < nw && my_m != 0) {
        int off = (grp == 1) ? __popcll(balls[0]) : 0;
        int pre = off + __popcll(my_ball & ((1ull << lane) - 1));
        list[pre] = my_l;
    }
    __syncthreads();

    const float4* fh4 = (const float4*)fh + (size_t)b * SEQ * D4;

    float4 a0 = make_float4(0.f, 0.f, 0.f, 0.f);
    float4 a1 = a0, a2 = a0;

    int i = grp;
    for (; i + 4 < n; i += 8) {                     // 2 rows / wave-iteration
        const float4* r0 = fh4 + (size_t)list[i]     * D4;
        const float4* r1 = fh4 + (size_t)list[i + 4] * D4;
        float4 x0 = r0[lane], x1 = r0[lane + 64], x2 = r0[lane + 128];
        float4 y0 = r1[lane], y1 = r1[lane + 64], y2 = r1[lane + 128];
        a0.x += x0.x + y0.x; a0.y += x0.y + y0.y;
        a0.z += x0.z + y0.z; a0.w += x0.w + y0.w;
        a1.x += x1.x + y1.x; a1.y += x1.y + y1.y;
        a1.z += x1.z + y1.z; a1.w += x1.w + y1.w;
        a2.x += x2.x + y2.x; a2.y += x2.y + y2.y;
        a2.z += x2.z + y2.z; a2.w += x2.w + y2.w;
    }
    if (i < n) {                                    // at most one leftover
        const float4* r0 = fh4 + (size_t)list[i] * D4;
        float4 x0 = r0[lane], x1 = r0[lane + 64], x2 = r0[lane + 128];
        a0.x += x0.x; a0.y += x0.y; a0.z += x0.z; a0.w += x0.w;
        a1.x += x1.x; a1.y += x1.y; a1.z += x1.z; a1.w += x1.w;
        a2.x += x2.x; a2.y += x2.y; a2.z += x2.z; a2.w += x2.w;
    }

    __shared__ float4 red[4][D4];                   // 12 KiB
    red[grp][lane]       = a0;
    red[grp][lane + 64]  = a1;
    red[grp][lane + 128] = a2;
    __syncthreads();

    if (tid < D4) {
        float4 r0 = red[0][tid], r1 = red[1][tid], r2 = red[2][tid], r3 = red[3][tid];
        float4 sum = make_float4(r0.x + r1.x + r2.x + r3.x,
                                 r0.y + r1.y + r2.y + r3.y,
                                 r0.z + r1.z + r2.z + r3.z,
                                 r0.w + r1.w + r2.w + r3.w);
        ((float4*)partial)[((size_t)b * S + s) * D4 + tid] = sum;
    }
}

// ---------------------------------------------------------------------------
// Kernel 2: reduce S partials, divide by mask count, 54 dot-products.
// grid = BATCH, block = 256 threads = 4 waves.
// ---------------------------------------------------------------------------
__global__ __launch_bounds__(256) void finalize_kernel(
    const float* __restrict__ partial, const int* __restrict__ mask,
    const float* __restrict__ W13, const float* __restrict__ b13,
    const float* __restrict__ W14, const float* __restrict__ b14,
    float* __restrict__ out, int S)
{
    const int b    = blockIdx.x;
    const int tid  = threadIdx.x;
    const int lane = tid & 63;
    const int wave = tid >> 6;

    // ---- valid-token count (sum of 512 {0,1} ints) ----
    int cnt = mask[b * SEQ + tid] + mask[b * SEQ + 256 + tid];
    for (int off = 32; off; off >>= 1) cnt += __shfl_down(cnt, off);
    __shared__ int wcnt[4];
    if (lane == 0) wcnt[wave] = cnt;

    __shared__ float pooled[DIM];
    __syncthreads();
    const float inv = 1.0f / (float)(wcnt[0] + wcnt[1] + wcnt[2] + wcnt[3]);

    // ---- reduce S segments -> pooled[d] ----
    if (tid < D4) {
        float4 acc = make_float4(0.f, 0.f, 0.f, 0.f);
        const float4* p4 = (const float4*)partial + (size_t)b * S * D4 + tid;
        for (int s = 0; s < S; ++s) {
            float4 v = p4[(size_t)s * D4];
            acc.x += v.x; acc.y += v.y; acc.z += v.z; acc.w += v.w;
        }
        ((float4*)pooled)[tid] =
            make_float4(acc.x * inv, acc.y * inv, acc.z * inv, acc.w * inv);
    }
    __syncthreads();

    // ---- 54 output dot-products, round-robin across the 4 waves ----
    for (int o = wave; o < NOUT; o += 4) {
        const float* Wrow = (o < 52) ? (W13 + (size_t)o * DIM)
                                     : (W14 + (size_t)(o - 52) * DIM);
        const float bias  = (o < 52) ? b13[o] : b14[o - 52];
        float acc = 0.f;
        #pragma unroll
        for (int j = 0; j < 12; ++j) {
            const int d = lane + 64 * j;
            acc = fmaf(pooled[d], Wrow[d], acc);
        }
        for (int off = 32; off; off >>= 1) acc += __shfl_down(acc, off);
        if (lane == 0) out[(size_t)b * NOUT + o] = acc + bias;
    }
}

// ---------------------------------------------------------------------------
// Inputs (setup_inputs order):
//   0: final_hidden  [256,512,768] f32   1: attention_mask [256,512] i32
//   2: W13 [13,4,768] f32               3: b13 [13,4] f32
//   4: W14 [2,768] f32                  5: b14 [2] f32
// Output: [256,54] f32.
// Workspace: partial sums [B][S][D] f32 = 6.29 MB at S=8 (adaptive shrink,
// floor S=4 so the compaction list fits 128 entries).
// ---------------------------------------------------------------------------
extern "C" void kernel_launch(void* const* d_in, const int* in_sizes, int n_in,
                              void* d_out, int out_size, void* d_ws, size_t ws_size,
                              hipStream_t stream) {
    const float* fh   = (const float*)d_in[0];
    const int*   mask = (const int*)d_in[1];
    const float* W13  = (const float*)d_in[2];
    const float* b13  = (const float*)d_in[3];
    const float* W14  = (const float*)d_in[4];
    const float* b14  = (const float*)d_in[5];
    float*       out  = (float*)d_out;
    float*       partial = (float*)d_ws;

    int S = 8;  // 2048 blocks -> 8 blocks/CU
    while (S > 4 && (size_t)BATCH * S * DIM * sizeof(float) > ws_size) S >>= 1;
    const int Ls = SEQ / S;

    pool_partial_kernel<<<dim3(BATCH * S), dim3(256), 0, stream>>>(
        fh, mask, partial, S, Ls);
    finalize_kernel<<<dim3(BATCH), dim3(256), 0, stream>>>(
        partial, mask, W13, b13, W14, b14, out, S);
}

// Round 3
// 486.863 us; speedup vs baseline: 1.0353x; 1.0252x over previous
//
#include <hip/hip_runtime.h>

// Problem constants (from reference): B=256, L=512, D=768, 54 outputs/row.
#define BATCH 256
#define SEQ   512
#define DIM   768
#define D4    (DIM / 4)   // 192 float4 per row
#define NOUT  54

// ---------------------------------------------------------------------------
// Single fused kernel: masked mean-pool + 54-way head projection.
// grid = 256 (one block per batch row, 1 block/CU), block = 1024 = 16 waves.
//
// Phase A: ballot-compact active (mask==1) row indices into LDS list.
//          (mask values are {0,1} -> active rows are pure adds, no multiply;
//           count n comes free from the ballots.)
// Phase B: branch-free streaming: wave w sums rows list[w + 16k], 2 rows per
//          iteration = 6 independent 1KB coalesced loads in flight per wave.
// Phase C: 16-wave LDS tree reduce -> pooled[768] (scaled by 1/n).
// Phase D: 54 dot-products round-robin across 16 waves, shuffle-reduce,
//          lane 0 writes out[b*54+o].
//
// No workspace, no second launch, no partial-sum HBM round-trip.
// ---------------------------------------------------------------------------
__global__ __launch_bounds__(1024) void bow_fused_kernel(
    const float* __restrict__ fh, const int* __restrict__ mask,
    const float* __restrict__ W13, const float* __restrict__ b13,
    const float* __restrict__ W14, const float* __restrict__ b14,
    float* __restrict__ out)
{
    const int b    = blockIdx.x;
    const int tid  = threadIdx.x;
    const int lane = tid & 63;
    const int wave = tid >> 6;   // 0..15

    __shared__ unsigned long long balls[8];
    __shared__ int   list[SEQ];
    __shared__ float pooled[DIM];

    // ---- Phase A: mask ballot + compaction (waves 0..7 cover 512 l's) ----
    int my_m = 0;
    if (wave < 8) {
        my_m = mask[b * SEQ + tid];
        unsigned long long bl = __ballot(my_m != 0);
        if (lane == 0) balls[wave] = bl;
    }
    __syncthreads();

    int n = 0;
    #pragma unroll
    for (int w = 0; w < 8; ++w) n += __popcll(balls[w]);

    if (wave < 8 && my_m != 0) {
        int off = 0;
        for (int w = 0; w < wave; ++w) off += __popcll(balls[w]);
        const unsigned long long bl = balls[wave];
        list[off + __popcll(bl & ((1ull << lane) - 1))] = tid;
    }
    __syncthreads();

    // ---- Phase B: stream active rows, 2 per wave-iteration ----
    const float4* fh4 = (const float4*)fh + (size_t)b * SEQ * D4;

    float4 a0 = make_float4(0.f, 0.f, 0.f, 0.f);
    float4 a1 = a0, a2 = a0;

    int i = wave;
    for (; i + 16 < n; i += 32) {
        const float4* r0 = fh4 + (size_t)list[i]      * D4;
        const float4* r1 = fh4 + (size_t)list[i + 16] * D4;
        float4 x0 = r0[lane], x1 = r0[lane + 64], x2 = r0[lane + 128];
        float4 y0 = r1[lane], y1 = r1[lane + 64], y2 = r1[lane + 128];
        a0.x += x0.x + y0.x; a0.y += x0.y + y0.y;
        a0.z += x0.z + y0.z; a0.w += x0.w + y0.w;
        a1.x += x1.x + y1.x; a1.y += x1.y + y1.y;
        a1.z += x1.z + y1.z; a1.w += x1.w + y1.w;
        a2.x += x2.x + y2.x; a2.y += x2.y + y2.y;
        a2.z += x2.z + y2.z; a2.w += x2.w + y2.w;
    }
    if (i < n) {
        const float4* r0 = fh4 + (size_t)list[i] * D4;
        float4 x0 = r0[lane], x1 = r0[lane + 64], x2 = r0[lane + 128];
        a0.x += x0.x; a0.y += x0.y; a0.z += x0.z; a0.w += x0.w;
        a1.x += x1.x; a1.y += x1.y; a1.z += x1.z; a1.w += x1.w;
        a2.x += x2.x; a2.y += x2.y; a2.z += x2.z; a2.w += x2.w;
    }

    // ---- Phase C: 16-wave reduce -> pooled ----
    __shared__ float4 red[16][D4];                  // 48 KiB
    red[wave][lane]       = a0;
    red[wave][lane + 64]  = a1;
    red[wave][lane + 128] = a2;
    __syncthreads();

    const float inv = 1.0f / (float)n;
    if (tid < D4) {
        float4 acc = make_float4(0.f, 0.f, 0.f, 0.f);
        #pragma unroll
        for (int w = 0; w < 16; ++w) {
            float4 v = red[w][tid];
            acc.x += v.x; acc.y += v.y; acc.z += v.z; acc.w += v.w;
        }
        ((float4*)pooled)[tid] =
            make_float4(acc.x * inv, acc.y * inv, acc.z * inv, acc.w * inv);
    }
    __syncthreads();

    // ---- Phase D: 54 output dot-products across 16 waves ----
    for (int o = wave; o < NOUT; o += 16) {
        const float* Wrow = (o < 52) ? (W13 + (size_t)o * DIM)
                                     : (W14 + (size_t)(o - 52) * DIM);
        const float bias  = (o < 52) ? b13[o] : b14[o - 52];
        float acc = 0.f;
        #pragma unroll
        for (int j = 0; j < 12; ++j) {
            const int d = lane + 64 * j;
            acc = fmaf(pooled[d], Wrow[d], acc);
        }
        for (int off = 32; off; off >>= 1) acc += __shfl_down(acc, off);
        if (lane == 0) out[(size_t)b * NOUT + o] = acc + bias;
    }
}

// ---------------------------------------------------------------------------
// Inputs (setup_inputs order):
//   0: final_hidden  [256,512,768] f32   1: attention_mask [256,512] i32
//   2: W13 [13,4,768] f32               3: b13 [13,4] f32
//   4: W14 [2,768] f32                  5: b14 [2] f32
// Output: [256,54] f32. Workspace: unused.
// ---------------------------------------------------------------------------
extern "C" void kernel_launch(void* const* d_in, const int* in_sizes, int n_in,
                              void* d_out, int out_size, void* d_ws, size_t ws_size,
                              hipStream_t stream) {
    const float* fh   = (const float*)d_in[0];
    const int*   mask = (const int*)d_in[1];
    const float* W13  = (const float*)d_in[2];
    const float* b13  = (const float*)d_in[3];
    const float* W14  = (const float*)d_in[4];
    const float* b14  = (const float*)d_in[5];
    float*       out  = (float*)d_out;

    bow_fused_kernel<<<dim3(BATCH), dim3(1024), 0, stream>>>(
        fh, mask, W13, b13, W14, b14, out);
}